// Round 1
// baseline (2344.632 us; speedup 1.0000x reference)
//
#include <hip/hip_runtime.h>

#define NRD 102   // D + XD

// ---------------- zero workspace (num, den, flags) ----------------
__global__ void k_zero(float* __restrict__ p, int n){
  int i = blockIdx.x*blockDim.x + threadIdx.x;
  if (i < n) p[i] = 0.f;
}

// ---------------- prep: transpose W panels, set tail flags ----------------
__global__ void k_prep(const float* __restrict__ W, const int* __restrict__ tail, int n_tail,
                       float* __restrict__ Bt, float* __restrict__ Wt3, int* __restrict__ flags){
  int i = blockIdx.x*blockDim.x + threadIdx.x;
  if (i < 102*192){
    int k = i/192, o = i - (i/192)*192;
    Bt[i] = (o < 96) ? W[o*300 + k] : W[(o-96)*300 + 102 + k];
  }
  int j = i - 102*192;
  if (j >= 0 && j < 96*96){
    int k = j/96, o = j - (j/96)*96;
    Wt3[j] = W[o*300 + 204 + k];
  }
  if (i < n_tail) flags[tail[i]] = 1;
}

// ---------------- masked scatter-sum (atomics) ----------------
__global__ void k_scatter(const float4* __restrict__ ea4, const float* __restrict__ mask,
                          const int* __restrict__ col, float* __restrict__ num,
                          float* __restrict__ den, int E){
  int i = blockIdx.x*blockDim.x + threadIdx.x;
  if (i >= E*24) return;
  int e = i/24, q = i - e*24;
  float m = mask[e];
  int c = col[e];
  float4 v = ea4[i];
  float* dst = num + (long)c*96 + q*4;
  unsafeAtomicAdd(dst+0, v.x*m);
  unsafeAtomicAdd(dst+1, v.y*m);
  unsafeAtomicAdd(dst+2, v.z*m);
  unsafeAtomicAdd(dst+3, v.w*m);
  if (q == 0) unsafeAtomicAdd(&den[c], m);
}

// ---------------- node_rep = [num/den, x], tail mix ----------------
__global__ void k_node(const float* __restrict__ num, const float* __restrict__ den,
                       const int* __restrict__ flags, const float* __restrict__ x,
                       const float* __restrict__ st, const int* __restrict__ change,
                       const int* __restrict__ is_support, float* __restrict__ out, int N){
  int i = blockIdx.x*blockDim.x + threadIdx.x;
  if (i >= N*NRD) return;
  int v = i/NRD, d = i - v*NRD;
  float val;
  if (d < 96) val = num[(long)v*96 + d] / (den[v] + 1.0f);
  else        val = x[v*6 + (d-96)];
  if (change[0] && !is_support[0] && flags[v]) val = 0.1f*st[d] + 0.9f*val;
  out[i] = val;
}

// ---------------- support-path tail mean (no-op when is_support==0) ----------------
__global__ void k_mean(const int* __restrict__ change, const int* __restrict__ is_support,
                       const int* __restrict__ tail, int n_tail, float* __restrict__ out){
  if (!(change[0] && is_support[0])) return;
  int d = threadIdx.x;
  if (d >= NRD) return;
  float s = 0.f;
  for (int i = 0; i < n_tail; i++) s += out[(long)tail[i]*NRD + d];
  s /= (float)n_tail;
  for (int i = 0; i < n_tail; i++) out[(long)tail[i]*NRD + d] = s;
}

// ---------------- P-GEMM: P1 = nr @ W1^T, P2 = nr @ W2^T ----------------
// tile 64 nodes x 192 outs, 256 thr, per-thread 4n x 12o
__launch_bounds__(256)
__global__ void k_pgemm(const float* __restrict__ nr, const float* __restrict__ Bt,
                        float* __restrict__ P1, float* __restrict__ P2, int N){
  __shared__ float A[64*106];   // stride 106 breaks bank aliasing across node rows
  __shared__ float B[34*192];
  int tid = threadIdx.x;
  int v0 = blockIdx.x*64;
  int nrows = N - v0; if (nrows > 64) nrows = 64;
  for (int idx = tid; idx < 64*102; idx += 256){
    int r = idx/102, c = idx - r*102;
    A[r*106 + c] = (idx < nrows*102) ? nr[(long)v0*102 + idx] : 0.f;
  }
  int ocol = tid & 15, nrow = tid >> 4;
  int o0 = ocol*12, n0 = nrow*4;
  float acc[4][12];
  #pragma unroll
  for (int i=0;i<4;i++){
    #pragma unroll
    for (int j=0;j<12;j++) acc[i][j] = 0.f;
  }
  for (int kc = 0; kc < 102; kc += 34){
    __syncthreads();
    for (int idx = tid; idx < 34*192; idx += 256) B[idx] = Bt[kc*192 + idx];
    __syncthreads();
    #pragma unroll
    for (int kk = 0; kk < 34; kk += 2){
      float2 a[4];
      #pragma unroll
      for (int i=0;i<4;i++) a[i] = *(const float2*)&A[(n0+i)*106 + kc + kk];
      float4 w0[3], w1[3];
      #pragma unroll
      for (int j=0;j<3;j++){
        w0[j] = *(const float4*)&B[ kk   *192 + o0 + j*4];
        w1[j] = *(const float4*)&B[(kk+1)*192 + o0 + j*4];
      }
      #pragma unroll
      for (int i=0;i<4;i++){
        #pragma unroll
        for (int j=0;j<3;j++){
          acc[i][j*4+0] = fmaf(a[i].y, w1[j].x, fmaf(a[i].x, w0[j].x, acc[i][j*4+0]));
          acc[i][j*4+1] = fmaf(a[i].y, w1[j].y, fmaf(a[i].x, w0[j].y, acc[i][j*4+1]));
          acc[i][j*4+2] = fmaf(a[i].y, w1[j].z, fmaf(a[i].x, w0[j].z, acc[i][j*4+2]));
          acc[i][j*4+3] = fmaf(a[i].y, w1[j].w, fmaf(a[i].x, w0[j].w, acc[i][j*4+3]));
        }
      }
    }
  }
  float* Pout = (o0 < 96) ? P1 : P2;
  int oo = (o0 < 96) ? o0 : (o0 - 96);
  #pragma unroll
  for (int i=0;i<4;i++){
    int v = v0 + n0 + i;
    if (v < N){
      #pragma unroll
      for (int j=0;j<3;j++){
        float4 t = make_float4(acc[i][j*4+0], acc[i][j*4+1], acc[i][j*4+2], acc[i][j*4+3]);
        *(float4*)&Pout[(long)v*96 + oo + j*4] = t;
      }
    }
  }
}

// ---------------- edge GEMM: out = ea @ W3^T + P1[row] + P2[col] + b ----------------
// tile 64 edges x 96 outs, 192 thr, per-thread 4e x 8o
__launch_bounds__(192)
__global__ void k_edge(const float* __restrict__ ea, const int* __restrict__ ei,
                       const float* __restrict__ P1, const float* __restrict__ P2,
                       const float* __restrict__ Wt3, const float* __restrict__ bias,
                       float* __restrict__ out, int E, int N){
  __shared__ float A[64*98];
  __shared__ float Wc[32*96];
  int tid = threadIdx.x;
  int e0 = blockIdx.x*64;
  int nrows = E - e0; if (nrows > 64) nrows = 64;
  for (int idx = tid; idx < 64*96; idx += 192){
    int r = idx/96, c = idx - r*96;
    A[r*98 + c] = (idx < nrows*96) ? ea[(long)e0*96 + idx] : 0.f;
  }
  int ocol = tid % 12, erow = tid / 12;
  int o0 = ocol*8, el0 = erow*4;
  float acc[4][8];
  #pragma unroll
  for (int i=0;i<4;i++){
    #pragma unroll
    for (int j=0;j<8;j++) acc[i][j] = 0.f;
  }
  for (int kc = 0; kc < 96; kc += 32){
    __syncthreads();
    for (int idx = tid; idx < 32*96; idx += 192) Wc[idx] = Wt3[kc*96 + idx];
    __syncthreads();
    #pragma unroll
    for (int kk = 0; kk < 32; kk += 2){
      float2 a[4];
      #pragma unroll
      for (int i=0;i<4;i++) a[i] = *(const float2*)&A[(el0+i)*98 + kc + kk];
      float4 w0[2], w1[2];
      #pragma unroll
      for (int j=0;j<2;j++){
        w0[j] = *(const float4*)&Wc[ kk   *96 + o0 + j*4];
        w1[j] = *(const float4*)&Wc[(kk+1)*96 + o0 + j*4];
      }
      #pragma unroll
      for (int i=0;i<4;i++){
        #pragma unroll
        for (int j=0;j<2;j++){
          acc[i][j*4+0] = fmaf(a[i].y, w1[j].x, fmaf(a[i].x, w0[j].x, acc[i][j*4+0]));
          acc[i][j*4+1] = fmaf(a[i].y, w1[j].y, fmaf(a[i].x, w0[j].y, acc[i][j*4+1]));
          acc[i][j*4+2] = fmaf(a[i].y, w1[j].z, fmaf(a[i].x, w0[j].z, acc[i][j*4+2]));
          acc[i][j*4+3] = fmaf(a[i].y, w1[j].w, fmaf(a[i].x, w0[j].w, acc[i][j*4+3]));
        }
      }
    }
  }
  const int* rowp = ei;
  const int* colp = ei + E;
  #pragma unroll
  for (int i=0;i<4;i++){
    int e = e0 + el0 + i;
    if (e < E){
      int r = rowp[e], c = colp[e];
      const float4* p1 = (const float4*)&P1[(long)r*96 + o0];
      const float4* p2 = (const float4*)&P2[(long)c*96 + o0];
      const float4* bb = (const float4*)&bias[o0];
      float4* op = (float4*)&out[(long)e*96 + o0];
      #pragma unroll
      for (int j=0;j<2;j++){
        float4 t;
        t.x = acc[i][j*4+0] + p1[j].x + p2[j].x + bb[j].x;
        t.y = acc[i][j*4+1] + p1[j].y + p2[j].y + bb[j].y;
        t.z = acc[i][j*4+2] + p1[j].z + p2[j].z + bb[j].z;
        t.w = acc[i][j*4+3] + p1[j].w + p2[j].w + bb[j].w;
        op[j] = t;
      }
    }
  }
}

extern "C" void kernel_launch(void* const* d_in, const int* in_sizes, int n_in,
                              void* d_out, int out_size, void* d_ws, size_t ws_size,
                              hipStream_t stream){
  const int*   change     = (const int*)d_in[0];
  const int*   is_support = (const int*)d_in[1];
  const int*   tail       = (const int*)d_in[3];
  const float* x          = (const float*)d_in[4];
  const int*   ei         = (const int*)d_in[5];
  const float* ea         = (const float*)d_in[6];
  const float* mask       = (const float*)d_in[7];
  const float* st         = (const float*)d_in[9];
  const float* W          = (const float*)d_in[10];
  const float* bias       = (const float*)d_in[11];
  int N = in_sizes[4]/6;
  int E = in_sizes[7];
  int n_tail = in_sizes[3];

  float* ws   = (float*)d_ws;
  float* num  = ws;                               // N*96  (reused as P1)
  float* den  = ws + (long)N*96;                  // N
  int*   flags= (int*)(ws + (long)N*97);          // N
  float* P2   = ws + (long)N*98;                  // N*96
  float* Bt   = ws + (long)N*98 + (long)N*96;     // 102*192
  float* Wt3  = Bt + 102*192;                     // 96*96

  float* out_node = (float*)d_out;                // N*102
  float* out_edge = out_node + (long)N*NRD;       // E*96

  int nz = N*98;
  hipLaunchKernelGGL(k_zero, dim3((nz+255)/256), dim3(256), 0, stream, ws, nz);
  hipLaunchKernelGGL(k_prep, dim3((102*192+96*96+255)/256), dim3(256), 0, stream,
                     W, tail, n_tail, Bt, Wt3, flags);
  hipLaunchKernelGGL(k_scatter, dim3((E*24+255)/256), dim3(256), 0, stream,
                     (const float4*)ea, mask, ei + E, num, den, E);
  hipLaunchKernelGGL(k_node, dim3((N*NRD+255)/256), dim3(256), 0, stream,
                     num, den, flags, x, st, change, is_support, out_node, N);
  hipLaunchKernelGGL(k_mean, dim3(1), dim3(128), 0, stream,
                     change, is_support, tail, n_tail, out_node);
  hipLaunchKernelGGL(k_pgemm, dim3((N+63)/64), dim3(256), 0, stream,
                     out_node, Bt, num, P2, N);
  hipLaunchKernelGGL(k_edge, dim3((E+63)/64), dim3(192), 0, stream,
                     ea, ei, num, P2, Wt3, bias, out_edge, E, N);
}

// Round 2
// 1525.636 us; speedup vs baseline: 1.5368x; 1.5368x over previous
//
#include <hip/hip_runtime.h>

#define NRD 102   // D + XD

// ---------------- zero int scratch (flags + cnt) ----------------
__global__ void k_zero_i(int* __restrict__ p, int n){
  int i = blockIdx.x*blockDim.x + threadIdx.x;
  if (i < n) p[i] = 0;
}

// ---------------- prep: transpose W panels, set tail flags ----------------
__global__ void k_prep(const float* __restrict__ W, const int* __restrict__ tail, int n_tail,
                       float* __restrict__ Bt, float* __restrict__ Wt3, int* __restrict__ flags){
  int i = blockIdx.x*blockDim.x + threadIdx.x;
  if (i < 102*192){
    int k = i/192, o = i - (i/192)*192;
    Bt[i] = (o < 96) ? W[o*300 + k] : W[(o-96)*300 + 102 + k];
  }
  int j = i - 102*192;
  if (j >= 0 && j < 96*96){
    int k = j/96, o = j - (j/96)*96;
    Wt3[j] = W[o*300 + 204 + k];
  }
  if (i < n_tail) flags[tail[i]] = 1;
}

// ---------------- CSR build: histogram ----------------
__global__ void k_hist(const int* __restrict__ col, int* __restrict__ cnt, int E){
  int e = blockIdx.x*blockDim.x + threadIdx.x;
  if (e < E) atomicAdd(&cnt[col[e]], 1);
}

// ---------------- CSR build: block-level exclusive scan ----------------
__global__ void k_scan1(const int* __restrict__ cnt, int* __restrict__ start,
                        int* __restrict__ bsum, int N){
  __shared__ int sh[256];
  int i = blockIdx.x*256 + threadIdx.x;
  int v = (i < N) ? cnt[i] : 0;
  sh[threadIdx.x] = v;
  __syncthreads();
  for (int off = 1; off < 256; off <<= 1){
    int t = (threadIdx.x >= off) ? sh[threadIdx.x - off] : 0;
    __syncthreads();
    sh[threadIdx.x] += t;
    __syncthreads();
  }
  if (i < N) start[i] = sh[threadIdx.x] - v;   // exclusive
  if (threadIdx.x == 255) bsum[blockIdx.x] = sh[255];
}

__global__ void k_scan2(int* __restrict__ bsum, int nb){
  if (threadIdx.x == 0){
    int acc = 0;
    for (int i = 0; i < nb; i++){ int t = bsum[i]; bsum[i] = acc; acc += t; }
  }
}

__global__ void k_scan3(int* __restrict__ start, int* __restrict__ cursor,
                        const int* __restrict__ bsum, int N){
  int i = blockIdx.x*256 + threadIdx.x;
  if (i < N){
    int s = start[i] + bsum[blockIdx.x];
    start[i] = s;
    cursor[i] = s;
  }
}

// ---------------- CSR build: fill edge ids ----------------
__global__ void k_fill(const int* __restrict__ col, int* __restrict__ cursor,
                       int* __restrict__ csr, int E){
  int e = blockIdx.x*blockDim.x + threadIdx.x;
  if (e < E){
    int p = atomicAdd(&cursor[col[e]], 1);
    csr[p] = e;
  }
}

// ---------------- gather-side segment mean + node_rep assembly ----------------
// block = (96,4): 4 nodes per block, 96 threads per node (one per dim)
__global__ void k_agg(const int* __restrict__ cnt, const int* __restrict__ start,
                      const int* __restrict__ csr, const float* __restrict__ ea,
                      const float* __restrict__ mask, const float* __restrict__ x,
                      const int* __restrict__ flags, const float* __restrict__ st,
                      const int* __restrict__ change, const int* __restrict__ is_support,
                      float* __restrict__ out, int N){
  int v = blockIdx.x*4 + threadIdx.y;
  if (v >= N) return;
  int tx = threadIdx.x;          // 0..95
  int deg = cnt[v], s = start[v];
  float vs = 0.f, ms = 0.f;
  for (int j = 0; j < deg; j++){
    int eid = csr[s + j];
    float m = mask[eid];
    vs += ea[(long)eid*96 + tx] * m;
    ms += m;
  }
  bool mix = change[0] && !is_support[0] && flags[v];
  float val = vs / (ms + 1.0f);
  if (mix) val = 0.1f*st[tx] + 0.9f*val;
  out[(long)v*NRD + tx] = val;
  if (tx < 6){
    float xv = x[v*6 + tx];
    if (mix) xv = 0.1f*st[96 + tx] + 0.9f*xv;
    out[(long)v*NRD + 96 + tx] = xv;
  }
}

// ---------------- support-path tail mean (no-op when is_support==0) ----------------
__global__ void k_mean(const int* __restrict__ change, const int* __restrict__ is_support,
                       const int* __restrict__ tail, int n_tail, float* __restrict__ out){
  if (!(change[0] && is_support[0])) return;
  int d = threadIdx.x;
  if (d >= NRD) return;
  float s = 0.f;
  for (int i = 0; i < n_tail; i++) s += out[(long)tail[i]*NRD + d];
  s /= (float)n_tail;
  for (int i = 0; i < n_tail; i++) out[(long)tail[i]*NRD + d] = s;
}

// ---------------- P-GEMM: P1 = nr @ W1^T, P2 = nr @ W2^T ----------------
__launch_bounds__(256)
__global__ void k_pgemm(const float* __restrict__ nr, const float* __restrict__ Bt,
                        float* __restrict__ P1, float* __restrict__ P2, int N){
  __shared__ float A[64*106];
  __shared__ float B[34*192];
  int tid = threadIdx.x;
  int v0 = blockIdx.x*64;
  int nrows = N - v0; if (nrows > 64) nrows = 64;
  for (int idx = tid; idx < 64*102; idx += 256){
    int r = idx/102, c = idx - r*102;
    A[r*106 + c] = (idx < nrows*102) ? nr[(long)v0*102 + idx] : 0.f;
  }
  int ocol = tid & 15, nrow = tid >> 4;
  int o0 = ocol*12, n0 = nrow*4;
  float acc[4][12];
  #pragma unroll
  for (int i=0;i<4;i++){
    #pragma unroll
    for (int j=0;j<12;j++) acc[i][j] = 0.f;
  }
  for (int kc = 0; kc < 102; kc += 34){
    __syncthreads();
    for (int idx = tid; idx < 34*192; idx += 256) B[idx] = Bt[kc*192 + idx];
    __syncthreads();
    #pragma unroll
    for (int kk = 0; kk < 34; kk += 2){
      float2 a[4];
      #pragma unroll
      for (int i=0;i<4;i++) a[i] = *(const float2*)&A[(n0+i)*106 + kc + kk];
      float4 w0[3], w1[3];
      #pragma unroll
      for (int j=0;j<3;j++){
        w0[j] = *(const float4*)&B[ kk   *192 + o0 + j*4];
        w1[j] = *(const float4*)&B[(kk+1)*192 + o0 + j*4];
      }
      #pragma unroll
      for (int i=0;i<4;i++){
        #pragma unroll
        for (int j=0;j<3;j++){
          acc[i][j*4+0] = fmaf(a[i].y, w1[j].x, fmaf(a[i].x, w0[j].x, acc[i][j*4+0]));
          acc[i][j*4+1] = fmaf(a[i].y, w1[j].y, fmaf(a[i].x, w0[j].y, acc[i][j*4+1]));
          acc[i][j*4+2] = fmaf(a[i].y, w1[j].z, fmaf(a[i].x, w0[j].z, acc[i][j*4+2]));
          acc[i][j*4+3] = fmaf(a[i].y, w1[j].w, fmaf(a[i].x, w0[j].w, acc[i][j*4+3]));
        }
      }
    }
  }
  float* Pout = (o0 < 96) ? P1 : P2;
  int oo = (o0 < 96) ? o0 : (o0 - 96);
  #pragma unroll
  for (int i=0;i<4;i++){
    int v = v0 + n0 + i;
    if (v < N){
      #pragma unroll
      for (int j=0;j<3;j++){
        float4 t = make_float4(acc[i][j*4+0], acc[i][j*4+1], acc[i][j*4+2], acc[i][j*4+3]);
        *(float4*)&Pout[(long)v*96 + oo + j*4] = t;
      }
    }
  }
}

// ---------------- edge GEMM: out = ea @ W3^T + P1[row] + P2[col] + b ----------------
// tile 128 edges x 96 outs, 256 thr, per-thread 8 edges (interleaved) x 6 outs
__launch_bounds__(256)
__global__ void k_edge(const float* __restrict__ ea, const int* __restrict__ ei,
                       const float* __restrict__ P1, const float* __restrict__ P2,
                       const float* __restrict__ Wt3, const float* __restrict__ bias,
                       float* __restrict__ out, int E, int N){
  __shared__ float A[128*100];   // stride 100: float4-aligned, rows land on distinct banks
  __shared__ float Wc[32*96];
  int tid = threadIdx.x;
  long e0 = (long)blockIdx.x*128;
  int nrows = E - (int)e0; if (nrows > 128) nrows = 128;
  if (nrows == 128){
    const float4* src = (const float4*)(ea + e0*96);
    for (int idx = tid; idx < 128*24; idx += 256){
      int r = idx/24, c = idx - r*24;
      *(float4*)&A[r*100 + c*4] = src[idx];
    }
  } else {
    for (int idx = tid; idx < 128*96; idx += 256){
      int r = idx/96, c = idx - r*96;
      A[r*100 + c] = (r < nrows) ? ea[e0*96 + idx] : 0.f;
    }
  }
  int ocol = tid & 15, erow = tid >> 4;   // 16 x 16
  int o0 = ocol*6;
  float acc[8][6];
  #pragma unroll
  for (int i=0;i<8;i++){
    #pragma unroll
    for (int j=0;j<6;j++) acc[i][j] = 0.f;
  }
  for (int kc = 0; kc < 96; kc += 32){
    __syncthreads();
    for (int idx = tid; idx < 32*24; idx += 256)
      ((float4*)Wc)[idx] = ((const float4*)(Wt3 + kc*96))[idx];
    __syncthreads();
    #pragma unroll
    for (int kk = 0; kk < 32; kk += 2){
      float2 a[8];
      #pragma unroll
      for (int i=0;i<8;i++) a[i] = *(const float2*)&A[(erow + 16*i)*100 + kc + kk];
      float2 w0[3], w1[3];
      #pragma unroll
      for (int j=0;j<3;j++){
        w0[j] = *(const float2*)&Wc[ kk   *96 + o0 + 2*j];
        w1[j] = *(const float2*)&Wc[(kk+1)*96 + o0 + 2*j];
      }
      #pragma unroll
      for (int i=0;i<8;i++){
        #pragma unroll
        for (int j=0;j<3;j++){
          acc[i][2*j]   = fmaf(a[i].y, w1[j].x, fmaf(a[i].x, w0[j].x, acc[i][2*j]));
          acc[i][2*j+1] = fmaf(a[i].y, w1[j].y, fmaf(a[i].x, w0[j].y, acc[i][2*j+1]));
        }
      }
    }
  }
  const int* rowp = ei;
  const int* colp = ei + E;
  #pragma unroll
  for (int i=0;i<8;i++){
    int el = erow + 16*i;
    if (el < nrows){
      long e = e0 + el;
      int r = rowp[e], c = colp[e];
      const float* p1 = P1 + (long)r*96 + o0;
      const float* p2 = P2 + (long)c*96 + o0;
      const float* bb = bias + o0;
      float* op = out + e*96 + o0;
      #pragma unroll
      for (int j=0;j<3;j++){
        float2 t;
        t.x = acc[i][2*j]   + p1[2*j]   + p2[2*j]   + bb[2*j];
        t.y = acc[i][2*j+1] + p1[2*j+1] + p2[2*j+1] + bb[2*j+1];
        *(float2*)&op[2*j] = t;
      }
    }
  }
}

extern "C" void kernel_launch(void* const* d_in, const int* in_sizes, int n_in,
                              void* d_out, int out_size, void* d_ws, size_t ws_size,
                              hipStream_t stream){
  const int*   change     = (const int*)d_in[0];
  const int*   is_support = (const int*)d_in[1];
  const int*   tail       = (const int*)d_in[3];
  const float* x          = (const float*)d_in[4];
  const int*   ei         = (const int*)d_in[5];
  const float* ea         = (const float*)d_in[6];
  const float* mask       = (const float*)d_in[7];
  const float* st         = (const float*)d_in[9];
  const float* W          = (const float*)d_in[10];
  const float* bias       = (const float*)d_in[11];
  int N = in_sizes[4]/6;
  int E = in_sizes[7];
  int n_tail = in_sizes[3];
  int nb = (N + 255)/256;

  float* ws   = (float*)d_ws;
  float* P1   = ws;                        // N*96
  float* P2   = P1 + (long)N*96;           // N*96
  float* Bt   = P2 + (long)N*96;           // 102*192
  float* Wt3  = Bt + 102*192;              // 96*96
  int*   flags  = (int*)(Wt3 + 96*96);     // N
  int*   cnt    = flags + N;               // N
  int*   startp = cnt + N;                 // N
  int*   cursor = startp + N;              // N
  int*   csr    = cursor + N;              // E
  int*   bsum   = csr + E;                 // nb (<512)

  float* out_node = (float*)d_out;             // N*102
  float* out_edge = out_node + (long)N*NRD;    // E*96

  hipLaunchKernelGGL(k_zero_i, dim3((2*N+255)/256), dim3(256), 0, stream, flags, 2*N);
  hipLaunchKernelGGL(k_prep, dim3((102*192+96*96+255)/256), dim3(256), 0, stream,
                     W, tail, n_tail, Bt, Wt3, flags);
  hipLaunchKernelGGL(k_hist, dim3((E+255)/256), dim3(256), 0, stream, ei + E, cnt, E);
  hipLaunchKernelGGL(k_scan1, dim3(nb), dim3(256), 0, stream, cnt, startp, bsum, N);
  hipLaunchKernelGGL(k_scan2, dim3(1), dim3(64), 0, stream, bsum, nb);
  hipLaunchKernelGGL(k_scan3, dim3(nb), dim3(256), 0, stream, startp, cursor, bsum, N);
  hipLaunchKernelGGL(k_fill, dim3((E+255)/256), dim3(256), 0, stream, ei + E, cursor, csr, E);
  hipLaunchKernelGGL(k_agg, dim3((N+3)/4), dim3(96,4), 0, stream,
                     cnt, startp, csr, ea, mask, x, flags, st, change, is_support, out_node, N);
  hipLaunchKernelGGL(k_mean, dim3(1), dim3(128), 0, stream,
                     change, is_support, tail, n_tail, out_node);
  hipLaunchKernelGGL(k_pgemm, dim3((N+63)/64), dim3(256), 0, stream,
                     out_node, Bt, P1, P2, N);
  hipLaunchKernelGGL(k_edge, dim3((E+127)/128), dim3(256), 0, stream,
                     ea, ei, P1, P2, Wt3, bias, out_edge, E, N);
}